// Round 3
// baseline (942.932 us; speedup 1.0000x reference)
//
#include <hip/hip_runtime.h>
#include <hip/hip_cooperative_groups.h>

namespace cg = cooperative_groups;

// B=16384, F=45, V=10000, D=256, H=32
// Linear MLP collapse (exact, verified absmax=0.0 in R1):
//   out[b] = sum_f tables[f, src[b,f]] . (W1@W2)  +  F*(b1@W2 + b2)
// Single cooperative kernel, 4 phases:
//   P0: w = W1@W2 into LDS (per block); zero referenced-row flags
//   P1: scatter flags from src (only ~80.6% of rows are referenced)
//   P2: t[r] = tables[r,:] . w   for referenced rows only (~371 MB stream)
//   P3: out[b] = sum_f t[f, src[b,f]] + F*c

#define BN 16384
#define FN 45
#define VN 10000
#define DN 256
#define HN 32
#define RN (FN * VN)      // 450000
#define NBLK 1024         // 4 blocks/CU on 256 CUs -> cooperative-safe
#define NTHR 256
#define NWAVE (NBLK * 4)  // 4096 waves
#define NTHREADS (NBLK * NTHR)

__global__ __launch_bounds__(NTHR, 4)
void fused_kernel(const int* __restrict__ src,
                  const float* __restrict__ tables,
                  const float* __restrict__ W1,
                  const float* __restrict__ b1,
                  const float* __restrict__ W2,
                  const float* __restrict__ b2,
                  float* __restrict__ out,
                  float* __restrict__ t,
                  unsigned char* __restrict__ flags) {
    cg::grid_group grid = cg::this_grid();
    const int tid = threadIdx.x;
    const int lane = tid & 63;
    const int wid = tid >> 6;
    const int gwave = blockIdx.x * 4 + wid;
    const int gtid = blockIdx.x * NTHR + tid;

    __shared__ __align__(16) float w_s[DN];
    __shared__ float c_s;

    // ---- P0a: w = W1 @ W2 (redundant per block; W1 is 32KB, L2-hit) ----
    {
        float s = 0.f;
#pragma unroll
        for (int h = 0; h < HN; ++h) s += W1[tid * HN + h] * W2[h];
        w_s[tid] = s;
        if (tid == 0) {
            float cc = 0.f;
#pragma unroll
            for (int h = 0; h < HN; ++h) cc += b1[h] * W2[h];
            c_s = (float)FN * (cc + b2[0]);
        }
    }
    // ---- P0b: zero flags (450000 bytes = 112500 words) ----
    {
        unsigned int* fw = reinterpret_cast<unsigned int*>(flags);
        for (int i = gtid; i < RN / 4; i += NTHREADS) fw[i] = 0u;
    }
    grid.sync();

    // ---- P1: scatter referenced-row flags ----
    for (int i = gtid; i < BN * FN; i += NTHREADS) {
        const int f = i % FN;
        flags[f * VN + src[i]] = (unsigned char)1;
    }
    grid.sync();

    // ---- P2: t[r] = tables[r,:] . w for referenced rows ----
    // One wave per row: 64 lanes x float4 = 256 floats = the whole row.
    {
        const float4 wv = reinterpret_cast<const float4*>(w_s)[lane];
        for (int r = gwave; r < RN; r += NWAVE) {
            if (!flags[r]) continue;  // uniform per wave; skips 1KB HBM read
            const float4 v =
                reinterpret_cast<const float4*>(tables + (size_t)r * DN)[lane];
            float s = v.x * wv.x + v.y * wv.y + v.z * wv.z + v.w * wv.w;
#pragma unroll
            for (int m = 1; m < 64; m <<= 1) s += __shfl_xor(s, m);
            if (lane == 0) t[r] = s;
        }
    }
    grid.sync();

    // ---- P3: out[b] = sum_f t[f, src[b,f]] + F*c ----
    for (int b = gwave; b < BN; b += NWAVE) {
        float s = 0.f;
        if (lane < FN) s = t[lane * VN + src[b * FN + lane]];
#pragma unroll
        for (int m = 1; m < 64; m <<= 1) s += __shfl_xor(s, m);
        if (lane == 0) out[b] = s + c_s;
    }
}

extern "C" void kernel_launch(void* const* d_in, const int* in_sizes, int n_in,
                              void* d_out, int out_size, void* d_ws, size_t ws_size,
                              hipStream_t stream) {
    const int* src = (const int*)d_in[0];
    const float* tables = (const float*)d_in[1];
    const float* W1 = (const float*)d_in[2];
    const float* b1 = (const float*)d_in[3];
    const float* W2 = (const float*)d_in[4];
    const float* b2 = (const float*)d_in[5];
    float* out = (float*)d_out;

    // Workspace: t = 450000 floats (1.8 MB), flags = 450000 bytes
    float* t = (float*)d_ws;
    unsigned char* flags = (unsigned char*)d_ws + (size_t)RN * sizeof(float);

    void* args[] = {(void*)&src, (void*)&tables, (void*)&W1, (void*)&b1,
                    (void*)&W2,  (void*)&b2,     (void*)&out, (void*)&t,
                    (void*)&flags};
    hipLaunchCooperativeKernel((void*)fused_kernel, dim3(NBLK), dim3(NTHR),
                               args, 0, stream);
}

// Round 8
// 630.811 us; speedup vs baseline: 1.4948x; 1.4948x over previous
//
#include <hip/hip_runtime.h>

// B=16384, F=45, V=10000, D=256, H=32
// Linear MLP collapse (exact, absmax=0.0 in R1/R3):
//   out[b] = sum_f tables[f, src[b,f]] . (W1@W2)  +  F*(b1@W2 + b2)
// R4 lesson: cooperative launch silently failed when VGPR pressure broke
// the 4-blocks/CU co-residency. R5: plain sequential launches.
//   K1: w = W1@W2, c = F*(b1@W2+b2)          (1 block)
//   memsetAsync: flags = 0                    (450 KB)
//   K2: scatter flags from src                (~80.6% rows referenced)
//   K3: t[r] = tables[r,:].w for flagged rows (thread-per-row, unrolled)
//   K4: out[b] = sum_f t[f, src[b,f]] + c    (thread-per-b, 45 unrolled)

#define BN 16384
#define FN 45
#define VN 10000
#define DN 256
#define HN 32
#define RN (FN * VN)  // 450000

// ---------------- K1: w = W1 @ W2, c = F*(b1@W2 + b2) ----------------
__global__ void prep_kernel(const float* __restrict__ W1,
                            const float* __restrict__ b1,
                            const float* __restrict__ W2,
                            const float* __restrict__ b2,
                            float* __restrict__ w_out,
                            float* __restrict__ c_out) {
    const int d = threadIdx.x;  // 0..255
    float s = 0.f;
#pragma unroll
    for (int h = 0; h < HN; ++h) s += W1[d * HN + h] * W2[h];
    w_out[d] = s;
    if (d == 0) {
        float cc = 0.f;
#pragma unroll
        for (int h = 0; h < HN; ++h) cc += b1[h] * W2[h];
        c_out[0] = (float)FN * (cc + b2[0]);
    }
}

// ---------------- K2: scatter referenced-row flags ----------------
__global__ void scatter_kernel(const int* __restrict__ src,
                               unsigned char* __restrict__ flags) {
    const int i = blockIdx.x * blockDim.x + threadIdx.x;  // < B*F exactly
    const int f = i % FN;
    flags[f * VN + src[i]] = (unsigned char)1;
}

// ---------------- K3: t[r] = tables[r,:] . w (thread per row) ----------------
// 64 independent float4 loads per row against LDS-broadcast w. Consecutive
// lanes stream consecutive rows; each 64B line fetched is fully consumed
// within 4 j-steps (L1-resident). Flag-masked lanes skip their 1KB row.
__global__ void row_dot_kernel(const float* __restrict__ tables,
                               const float* __restrict__ w_glob,
                               const unsigned char* __restrict__ flags,
                               float* __restrict__ t) {
    __shared__ __align__(16) float w_s[DN];
    w_s[threadIdx.x] = w_glob[threadIdx.x];
    __syncthreads();

    const int r = blockIdx.x * blockDim.x + threadIdx.x;
    if (r >= RN) return;
    if (!flags[r]) return;

    const float4* __restrict__ row =
        reinterpret_cast<const float4*>(tables + (size_t)r * DN);
    const float4* __restrict__ wv4 = reinterpret_cast<const float4*>(w_s);
    float s = 0.f;
#pragma unroll
    for (int j = 0; j < DN / 4; ++j) {
        const float4 v = row[j];
        const float4 wv = wv4[j];  // LDS broadcast, conflict-free
        s += v.x * wv.x + v.y * wv.y + v.z * wv.z + v.w * wv.w;
    }
    t[r] = s;
}

// ---------------- K4: out[b] = sum_f t[f, src[b,f]] + c ----------------
// Thread per b: 45 independent src loads + 45 independent gathers from the
// 1.8MB L2-resident t. No cross-lane ops.
__global__ void gather_kernel(const int* __restrict__ src,
                              const float* __restrict__ t,
                              const float* __restrict__ c,
                              float* __restrict__ out) {
    const int b = blockIdx.x * blockDim.x + threadIdx.x;  // < BN exactly
    const int* __restrict__ s_row = src + (size_t)b * FN;
    float s = 0.f;
#pragma unroll
    for (int f = 0; f < FN; ++f) {
        s += t[f * VN + s_row[f]];
    }
    out[b] = s + c[0];
}

extern "C" void kernel_launch(void* const* d_in, const int* in_sizes, int n_in,
                              void* d_out, int out_size, void* d_ws, size_t ws_size,
                              hipStream_t stream) {
    const int* src = (const int*)d_in[0];
    const float* tables = (const float*)d_in[1];
    const float* W1 = (const float*)d_in[2];
    const float* b1 = (const float*)d_in[3];
    const float* W2 = (const float*)d_in[4];
    const float* b2 = (const float*)d_in[5];
    float* out = (float*)d_out;

    // Workspace layout (bytes): [0, 1.8M) t | then w(256f) | c(1f) | flags(450K)
    float* t = (float*)d_ws;
    float* w = t + RN;
    float* c = w + DN;
    unsigned char* flags = (unsigned char*)(c + 1);

    prep_kernel<<<1, 256, 0, stream>>>(W1, b1, W2, b2, w, c);
    hipMemsetAsync(flags, 0, RN, stream);
    scatter_kernel<<<(BN * FN) / 256, 256, 0, stream>>>(src, flags);  // 2880 blocks
    row_dot_kernel<<<(RN + 255) / 256, 256, 0, stream>>>(tables, w, flags, t);
    gather_kernel<<<BN / 256, 256, 0, stream>>>(src, t, c, out);      // 64 blocks
}

// Round 9
// 606.530 us; speedup vs baseline: 1.5546x; 1.0400x over previous
//
#include <hip/hip_runtime.h>

// B=16384, F=45, V=10000, D=256, H=32
// Linear MLP collapse (exact, absmax=0.0 verified):
//   out[b] = sum_f tables[f, src[b,f]] . (W1@W2)  +  F*(b1@W2 + b2)
// R8 lesson: thread-per-row dot = stride-1024B lanes -> L1 thrash (~180us).
// R9: wave-per-8-consecutive-rows. Coalesced (64 lanes x float4 = 1 row),
// 8 rows batched per wave: one uniform u64 flag load, 8 loads in flight,
// 8 independent butterfly-reduce chains (ILP hides swizzle latency).

#define BN 16384
#define FN 45
#define VN 10000
#define DN 256
#define HN 32
#define RN (FN * VN)  // 450000

// ---------------- K1: w = W1 @ W2, c = F*(b1@W2 + b2) ----------------
__global__ void prep_kernel(const float* __restrict__ W1,
                            const float* __restrict__ b1,
                            const float* __restrict__ W2,
                            const float* __restrict__ b2,
                            float* __restrict__ w_out,
                            float* __restrict__ c_out) {
    const int d = threadIdx.x;  // 0..255
    float s = 0.f;
#pragma unroll
    for (int h = 0; h < HN; ++h) s += W1[d * HN + h] * W2[h];
    w_out[d] = s;
    if (d == 0) {
        float cc = 0.f;
#pragma unroll
        for (int h = 0; h < HN; ++h) cc += b1[h] * W2[h];
        c_out[0] = (float)FN * (cc + b2[0]);
    }
}

// ---------------- K2: scatter referenced-row flags ----------------
__global__ void scatter_kernel(const int* __restrict__ src,
                               unsigned char* __restrict__ flags) {
    const int i = blockIdx.x * blockDim.x + threadIdx.x;  // < B*F exactly
    const int f = i % FN;
    flags[f * VN + src[i]] = (unsigned char)1;
}

// ---------------- K3: t[r] = tables[r,:] . w  (wave per 8 rows) ----------------
// Wave g handles rows [8g, 8g+8). Flags for the 8 rows arrive as one
// uniform u64 (wave-uniform scalar branches). Row loads are coalesced:
// lane l reads float4 l of the row (64 x 16B = 1KB). 8 independent
// accumulators -> 8 loads in flight, 8 interleaved shfl-reduce chains.
__global__ __launch_bounds__(256)
void row_dot_kernel(const float* __restrict__ tables,
                    const float* __restrict__ w_glob,
                    const unsigned long long* __restrict__ flags8,
                    float* __restrict__ t) {
    const int lane = threadIdx.x & 63;
    const int g = (blockIdx.x * blockDim.x + threadIdx.x) >> 6;  // wave id
    const int r0 = g * 8;
    if (r0 >= RN) return;

    // Per-lane weight fragment (uniform across rows; 4 VGPRs, loaded once)
    const float4 wv = reinterpret_cast<const float4*>(w_glob)[lane];

    const unsigned long long fl = flags8[g];  // uniform address -> broadcast
    if (fl == 0ull) return;

    const float4* __restrict__ base =
        reinterpret_cast<const float4*>(tables) + (size_t)r0 * (DN / 4);

    float4 v[8];
#pragma unroll
    for (int k = 0; k < 8; ++k) {
        if ((fl >> (8 * k)) & 0xFFull) v[k] = base[k * (DN / 4) + lane];
    }
    float s[8];
#pragma unroll
    for (int k = 0; k < 8; ++k) {
        if ((fl >> (8 * k)) & 0xFFull) {
            s[k] = v[k].x * wv.x + v[k].y * wv.y + v[k].z * wv.z + v[k].w * wv.w;
        }
    }
#pragma unroll
    for (int k = 0; k < 8; ++k) {
        if ((fl >> (8 * k)) & 0xFFull) {
#pragma unroll
            for (int m = 1; m < 64; m <<= 1) s[k] += __shfl_xor(s[k], m);
            if (lane == 0) t[r0 + k] = s[k];
        }
    }
}

// ---------------- K4: out[b] = sum_f t[f, src[b,f]] + c ----------------
__global__ void gather_kernel(const int* __restrict__ src,
                              const float* __restrict__ t,
                              const float* __restrict__ c,
                              float* __restrict__ out) {
    const int b = blockIdx.x * blockDim.x + threadIdx.x;  // < BN exactly
    const int* __restrict__ s_row = src + (size_t)b * FN;
    float s = 0.f;
#pragma unroll
    for (int f = 0; f < FN; ++f) {
        s += t[f * VN + s_row[f]];
    }
    out[b] = s + c[0];
}

extern "C" void kernel_launch(void* const* d_in, const int* in_sizes, int n_in,
                              void* d_out, int out_size, void* d_ws, size_t ws_size,
                              hipStream_t stream) {
    const int* src = (const int*)d_in[0];
    const float* tables = (const float*)d_in[1];
    const float* W1 = (const float*)d_in[2];
    const float* b1 = (const float*)d_in[3];
    const float* W2 = (const float*)d_in[4];
    const float* b2 = (const float*)d_in[5];
    float* out = (float*)d_out;

    // ws layout (bytes): [0,1.8M) t | [1.8M,+450K) flags (8B-aligned) |
    //                    then w (16B-aligned: 2250000%16==0) | c
    float* t = (float*)d_ws;
    unsigned char* flags = (unsigned char*)d_ws + (size_t)RN * 4;   // 1800000
    float* w = (float*)((unsigned char*)d_ws + (size_t)RN * 5);     // 2250000
    float* c = w + DN;

    prep_kernel<<<1, 256, 0, stream>>>(W1, b1, W2, b2, w, c);
    hipMemsetAsync(flags, 0, RN, stream);
    scatter_kernel<<<(BN * FN) / 256, 256, 0, stream>>>(src, flags);  // 2880 blk
    // 450000/8 = 56250 waves; 4 waves/block -> 14063 blocks
    row_dot_kernel<<<(RN / 8 + 3) / 4, 256, 0, stream>>>(
        tables, w, (const unsigned long long*)flags, t);
    gather_kernel<<<BN / 256, 256, 0, stream>>>(src, t, c, out);      // 64 blk
}